// Round 22
// baseline (594.897 us; speedup 1.0000x reference)
//
#include <hip/hip_runtime.h>

#define SEPS 1e-10f

typedef float v2f __attribute__((ext_vector_type(2)));

__device__ __forceinline__ float fast_rcp(float x) { return __builtin_amdgcn_rcpf(x); }
__device__ __forceinline__ float fast_exp(float x) { return __expf(x); }
__device__ __forceinline__ float fast_sigmoid(float x) {
    return fast_rcp(1.0f + fast_exp(-x));
}
__device__ __forceinline__ v2f splat2(float x) { v2f r; r.x = x; r.y = x; return r; }

// Prep kernel (same as r19): repack W1(+b1) and W4 into request-friendly rows.
//  W1T[64][8]: [k][0..5]=W1[i][k], [6]=b1[k], [7]=pad
//  W4T[16][12]: [k][0..8]=W4[k][j], pad 3
__global__ void sinkhorn_prep_kernel(
    const float* __restrict__ W1, const float* __restrict__ b1,
    const float* __restrict__ W4, float* __restrict__ ws)
{
    int t = threadIdx.x;
    if (t < 64) {
#pragma unroll
        for (int i = 0; i < 6; ++i) ws[t * 8 + i] = W1[i * 64 + t];
        ws[t * 8 + 6] = b1[t];
        ws[t * 8 + 7] = 0.0f;
    } else if (t >= 64 && t < 80) {
        int k = t - 64;
#pragma unroll
        for (int j = 0; j < 9; ++j) ws[512 + k * 12 + j] = W4[k * 9 + j];
        ws[512 + k * 12 + 9]  = 0.0f;
        ws[512 + k * 12 + 10] = 0.0f;
        ws[512 + k * 12 + 11] = 0.0f;
    }
}

// r19 structure + CONVOY-BREAKING k-rotation: each wave starts its L1+L2
// k-loop at a wave/block-dependent offset (multiples of 8 k's). Theory: all
// resident waves otherwise run the identical s_load burst schedule -> K$
// convoy -> ~67% of SIMD cycles all waves wait in the same lgkmcnt. Phased
// waves overlap one wave's SMEM wait with others' FMA bursts. Accumulation
// order over k is mathematically order-independent; per-thread arrays stay
// compile-time-indexed (only uniform weight ADDRESSES become runtime-uniform,
// which stays on the scalar pipe).
__global__ __launch_bounds__(256)
__attribute__((amdgpu_waves_per_eu(4, 8)))
void sinkhorn_mlp_kernel(
    const float* __restrict__ margins,
    const float* __restrict__ w1t,    // d_ws: W1T[64][8]
    const float* __restrict__ W2, const float* __restrict__ b2,
    const float* __restrict__ W3, const float* __restrict__ b3,
    const float* __restrict__ w4t,    // d_ws+512: W4T[16][12]
    const float* __restrict__ b4,
    float* __restrict__ out_mus, float* __restrict__ out_V, int n)
{
    int r = blockIdx.x * blockDim.x + threadIdx.x;
    if (r >= n) return;

    // wave-uniform rotation offset: k-pair chunks of 2, offset in {0,4,...,28}
    // (i.e. k offsets {0,8,...,56}) spread across 4 waves/block x 2 block phases
    const int wv = threadIdx.x >> 6;
    const int coff = ((wv + ((blockIdx.x & 1) << 2)) << 2) & 31;

    // ---- load margins (6 floats, 8B-aligned) ----
    const float2* mp = reinterpret_cast<const float2*>(margins + (size_t)r * 6);
    float2 mv0 = mp[0], mv1 = mp[1], mv2 = mp[2];
    float m0 = mv0.x, m1 = mv0.y, m2 = mv1.x, m3 = mv1.y, m4 = mv2.x, m5 = mv2.y;

    // ---- layers 1+2 fused, j packed; k visited in rotated order ----
    v2f h2p[16];
    const v2f* b2v = reinterpret_cast<const v2f*>(b2);
#pragma unroll
    for (int jp = 0; jp < 16; ++jp) h2p[jp] = b2v[jp];

#pragma unroll 1
    for (int c0 = 0; c0 < 32; ++c0) {
        const int c = (c0 + coff) & 31;       // rotated k-pair index (uniform)
        const int kbase = c << 1;
        const float* w1r = w1t + kbase * 8;   // 16 contiguous floats (2 rows)
        const float* w2r = W2 + kbase * 32;   // 64 contiguous floats (2 rows)

        // k = kbase
        float ta = w1r[6];
        ta = fmaf(m0, w1r[0], ta);
        ta = fmaf(m1, w1r[1], ta);
        ta = fmaf(m2, w1r[2], ta);
        ta = fmaf(m3, w1r[3], ta);
        ta = fmaf(m4, w1r[4], ta);
        ta = fmaf(m5, w1r[5], ta);
        v2f tva = splat2(fmaxf(ta, 0.0f));
        // k = kbase + 1
        float tb = w1r[8 + 6];
        tb = fmaf(m0, w1r[8 + 0], tb);
        tb = fmaf(m1, w1r[8 + 1], tb);
        tb = fmaf(m2, w1r[8 + 2], tb);
        tb = fmaf(m3, w1r[8 + 3], tb);
        tb = fmaf(m4, w1r[8 + 4], tb);
        tb = fmaf(m5, w1r[8 + 5], tb);
        v2f tvb = splat2(fmaxf(tb, 0.0f));

        const v2f* w2a = reinterpret_cast<const v2f*>(w2r);
        const v2f* w2b = reinterpret_cast<const v2f*>(w2r + 32);
#pragma unroll
        for (int jp = 0; jp < 16; ++jp)
            h2p[jp] = __builtin_elementwise_fma(tva, w2a[jp], h2p[jp]);
#pragma unroll
        for (int jp = 0; jp < 16; ++jp)
            h2p[jp] = __builtin_elementwise_fma(tvb, w2b[jp], h2p[jp]);
    }

    // ---- layer 3 fused, packed (k order fixed: h2p is k-indexed) ----
    v2f h3p[8];
    const v2f* b3v = reinterpret_cast<const v2f*>(b3);
#pragma unroll
    for (int jp = 0; jp < 8; ++jp) h3p[jp] = b3v[jp];
#pragma unroll
    for (int k = 0; k < 32; ++k) {
        float hk = (k & 1) ? h2p[k >> 1].y : h2p[k >> 1].x;   // compile-time select
        float t = fmaxf(hk, 0.0f);
        v2f tv = splat2(t);
        const v2f* w3r = reinterpret_cast<const v2f*>(W3 + k * 16);
#pragma unroll
        for (int jp = 0; jp < 8; ++jp)
            h3p[jp] = __builtin_elementwise_fma(tv, w3r[jp], h3p[jp]);
    }

    // ---- layer 4 fused, scalar (padded 12-stride rows from prep) ----
    float pars[9];
#pragma unroll
    for (int j = 0; j < 9; ++j) pars[j] = b4[j];
#pragma unroll
    for (int k = 0; k < 16; ++k) {
        float hk = (k & 1) ? h3p[k >> 1].y : h3p[k >> 1].x;
        float t = fmaxf(hk, 0.0f);
        const float* w4r = w4t + k * 12;
#pragma unroll
        for (int j = 0; j < 9; ++j) pars[j] = fmaf(t, w4r[j], pars[j]);
    }

    // ---- heads ----
    float p0 = fast_exp(pars[0]);
    float p1 = fast_exp(pars[1]);
    float p2 = fast_exp(pars[2]);
    float p3 = fast_exp(pars[3]);

    float A00 = p3 * p0, A01 = p3 * p1, A02 = p3 * p2;
    float A10 = p3 * p1, A11 = p3 * p0, A12 = p3 * p1;
    float A20 = p3 * p2, A21 = p3 * p1, A22 = p3 * p0;

    float sm0 = fast_sigmoid(pars[4]);
    float sm1 = fast_sigmoid(pars[5]);
    float sf0 = fast_sigmoid(pars[6]);
    float sf1 = fast_sigmoid(pars[7]);
    float V   = fast_exp(pars[8]);

    float rc0 = m0 * sm0, rc1 = m1 * sm1, rc2 = m2;   // row targets
    float cc0 = m3 * sf0, cc1 = m4 * sf1, cc2 = m5;   // col targets
    float mum0_0 = m0 * (1.0f - sm0);
    float mum0_1 = m1 * (1.0f - sm1);
    float mu0f_0 = m3 * (1.0f - sf0);
    float mu0f_1 = m4 * (1.0f - sf1);

    // ---- Sinkhorn: 10 iterations (register-resident 3x3, scalar) ----
#pragma unroll
    for (int it = 0; it < 10; ++it) {
        float f0 = rc0 * fast_rcp(A00 + A01 + A02 + SEPS);
        float f1 = rc1 * fast_rcp(A10 + A11 + A12 + SEPS);
        float f2 = rc2 * fast_rcp(A20 + A21 + A22 + SEPS);
        A00 *= f0; A01 *= f0; A02 *= f0;
        A10 *= f1; A11 *= f1; A12 *= f1;
        A20 *= f2; A21 *= f2; A22 *= f2;
        float g0 = cc0 * fast_rcp(A00 + A10 + A20 + SEPS);
        float g1 = cc1 * fast_rcp(A01 + A11 + A21 + SEPS);
        float g2 = cc2 * fast_rcp(A02 + A12 + A22 + SEPS);
        A00 *= g0; A10 *= g0; A20 *= g0;
        A01 *= g1; A11 *= g1; A21 *= g1;
        A02 *= g2; A12 *= g2; A22 *= g2;
    }

    // ---- output: mus (4x4 row-major) then V ----
    float4* o = reinterpret_cast<float4*>(out_mus + (size_t)r * 16);
    o[0] = make_float4(A00, A01, A02, mum0_0);
    o[1] = make_float4(A10, A11, A12, mum0_1);
    o[2] = make_float4(A20, A21, A22, 0.0f);
    o[3] = make_float4(mu0f_0, mu0f_1, 0.0f, 0.0f);
    out_V[r] = V;
}

extern "C" void kernel_launch(void* const* d_in, const int* in_sizes, int n_in,
                              void* d_out, int out_size, void* d_ws, size_t ws_size,
                              hipStream_t stream) {
    const float* margins = (const float*)d_in[0];
    const float* W1 = (const float*)d_in[1];
    const float* b1 = (const float*)d_in[2];
    const float* W2 = (const float*)d_in[3];
    const float* b2 = (const float*)d_in[4];
    const float* W3 = (const float*)d_in[5];
    const float* b3 = (const float*)d_in[6];
    const float* W4 = (const float*)d_in[7];
    const float* b4 = (const float*)d_in[8];

    int n = in_sizes[0] / 6;
    float* out_mus = (float*)d_out;
    float* out_V   = out_mus + (size_t)n * 16;
    float* ws      = (float*)d_ws;   // needs 704 floats = 2816 B

    sinkhorn_prep_kernel<<<1, 256, 0, stream>>>(W1, b1, W4, ws);

    dim3 block(256);
    dim3 grid((n + 255) / 256);
    sinkhorn_mlp_kernel<<<grid, block, 0, stream>>>(
        margins, ws, W2, b2, W3, b3, ws + 512, b4, out_mus, out_V, n);
}

// Round 23
// 155.724 us; speedup vs baseline: 3.8202x; 3.8202x over previous
//
#include <hip/hip_runtime.h>

#define SEPS 1e-10f

typedef float v2f __attribute__((ext_vector_type(2)));

__device__ __forceinline__ float fast_rcp(float x) { return __builtin_amdgcn_rcpf(x); }
__device__ __forceinline__ float fast_exp(float x) { return __expf(x); }
__device__ __forceinline__ float fast_sigmoid(float x) {
    return fast_rcp(1.0f + fast_exp(-x));
}
__device__ __forceinline__ v2f splat2(float x) { v2f r; r.x = x; r.y = x; return r; }

// Prep kernel (same as r19): repack W1(+b1) and W4 into request-friendly rows.
//  W1T[64][8]: [k][0..5]=W1[i][k], [6]=b1[k], [7]=pad
//  W4T[16][12]: [k][0..8]=W4[k][j], pad 3
__global__ void sinkhorn_prep_kernel(
    const float* __restrict__ W1, const float* __restrict__ b1,
    const float* __restrict__ W4, float* __restrict__ ws)
{
    int t = threadIdx.x;
    if (t < 64) {
#pragma unroll
        for (int i = 0; i < 6; ++i) ws[t * 8 + i] = W1[i * 64 + t];
        ws[t * 8 + 6] = b1[t];
        ws[t * 8 + 7] = 0.0f;
    } else if (t >= 64 && t < 80) {
        int k = t - 64;
#pragma unroll
        for (int j = 0; j < 9; ++j) ws[512 + k * 12 + j] = W4[k * 9 + j];
        ws[512 + k * 12 + 9]  = 0.0f;
        ws[512 + k * 12 + 10] = 0.0f;
        ws[512 + k * 12 + 11] = 0.0f;
    }
}

// r19 structure + convoy-breaking k-rotation, done RIGHT this time:
// the rotation offset goes through __builtin_amdgcn_readfirstlane so the
// compiler's divergence analysis knows it is wave-uniform -> weight addresses
// stay uniform -> s_load stream preserved (r22 failed because threadIdx-derived
// offsets were not provably uniform -> whole weight stream fell to per-lane
// global_load, 3.5x regression, SGPR 96->64).
// Theory: ~113us of r19's 178 is all-waves-simultaneously-in-lgkmcnt (convoy:
// identical k schedules). Per-wave phase rotation staggers SMEM bursts so one
// wave's wait overlaps other waves' FMA bursts.
__global__ __launch_bounds__(256)
__attribute__((amdgpu_waves_per_eu(4, 8)))
void sinkhorn_mlp_kernel(
    const float* __restrict__ margins,
    const float* __restrict__ w1t,    // d_ws: W1T[64][8]
    const float* __restrict__ W2, const float* __restrict__ b2,
    const float* __restrict__ W3, const float* __restrict__ b3,
    const float* __restrict__ w4t,    // d_ws+512: W4T[16][12]
    const float* __restrict__ b4,
    float* __restrict__ out_mus, float* __restrict__ out_V, int n)
{
    int r = blockIdx.x * blockDim.x + threadIdx.x;
    if (r >= n) return;

    // wave-uniform (SGPR-resident) rotation offset in k-pairs: {0,4,...,28}
    const int wv = __builtin_amdgcn_readfirstlane(threadIdx.x >> 6);
    const int coff = ((wv + ((blockIdx.x & 1) << 2)) << 2) & 31;

    // ---- load margins (6 floats, 8B-aligned) ----
    const float2* mp = reinterpret_cast<const float2*>(margins + (size_t)r * 6);
    float2 mv0 = mp[0], mv1 = mp[1], mv2 = mp[2];
    float m0 = mv0.x, m1 = mv0.y, m2 = mv1.x, m3 = mv1.y, m4 = mv2.x, m5 = mv2.y;

    // ---- layers 1+2 fused, j packed; k visited in rotated order ----
    v2f h2p[16];
    const v2f* b2v = reinterpret_cast<const v2f*>(b2);
#pragma unroll
    for (int jp = 0; jp < 16; ++jp) h2p[jp] = b2v[jp];

#pragma unroll 1
    for (int c0 = 0; c0 < 32; ++c0) {
        const int c = (c0 + coff) & 31;       // uniform (SGPR) k-pair index
        const int kbase = c << 1;
        const float* w1r = w1t + kbase * 8;   // 16 contiguous floats (2 rows)
        const float* w2r = W2 + kbase * 32;   // 64 contiguous floats (2 rows)

        // k = kbase
        float ta = w1r[6];
        ta = fmaf(m0, w1r[0], ta);
        ta = fmaf(m1, w1r[1], ta);
        ta = fmaf(m2, w1r[2], ta);
        ta = fmaf(m3, w1r[3], ta);
        ta = fmaf(m4, w1r[4], ta);
        ta = fmaf(m5, w1r[5], ta);
        v2f tva = splat2(fmaxf(ta, 0.0f));
        // k = kbase + 1
        float tb = w1r[8 + 6];
        tb = fmaf(m0, w1r[8 + 0], tb);
        tb = fmaf(m1, w1r[8 + 1], tb);
        tb = fmaf(m2, w1r[8 + 2], tb);
        tb = fmaf(m3, w1r[8 + 3], tb);
        tb = fmaf(m4, w1r[8 + 4], tb);
        tb = fmaf(m5, w1r[8 + 5], tb);
        v2f tvb = splat2(fmaxf(tb, 0.0f));

        const v2f* w2a = reinterpret_cast<const v2f*>(w2r);
        const v2f* w2b = reinterpret_cast<const v2f*>(w2r + 32);
#pragma unroll
        for (int jp = 0; jp < 16; ++jp)
            h2p[jp] = __builtin_elementwise_fma(tva, w2a[jp], h2p[jp]);
#pragma unroll
        for (int jp = 0; jp < 16; ++jp)
            h2p[jp] = __builtin_elementwise_fma(tvb, w2b[jp], h2p[jp]);
    }

    // ---- layer 3 fused, packed ----
    v2f h3p[8];
    const v2f* b3v = reinterpret_cast<const v2f*>(b3);
#pragma unroll
    for (int jp = 0; jp < 8; ++jp) h3p[jp] = b3v[jp];
#pragma unroll
    for (int k = 0; k < 32; ++k) {
        float hk = (k & 1) ? h2p[k >> 1].y : h2p[k >> 1].x;   // compile-time select
        float t = fmaxf(hk, 0.0f);
        v2f tv = splat2(t);
        const v2f* w3r = reinterpret_cast<const v2f*>(W3 + k * 16);
#pragma unroll
        for (int jp = 0; jp < 8; ++jp)
            h3p[jp] = __builtin_elementwise_fma(tv, w3r[jp], h3p[jp]);
    }

    // ---- layer 4 fused, scalar (padded 12-stride rows from prep) ----
    float pars[9];
#pragma unroll
    for (int j = 0; j < 9; ++j) pars[j] = b4[j];
#pragma unroll
    for (int k = 0; k < 16; ++k) {
        float hk = (k & 1) ? h3p[k >> 1].y : h3p[k >> 1].x;
        float t = fmaxf(hk, 0.0f);
        const float* w4r = w4t + k * 12;
#pragma unroll
        for (int j = 0; j < 9; ++j) pars[j] = fmaf(t, w4r[j], pars[j]);
    }

    // ---- heads ----
    float p0 = fast_exp(pars[0]);
    float p1 = fast_exp(pars[1]);
    float p2 = fast_exp(pars[2]);
    float p3 = fast_exp(pars[3]);

    float A00 = p3 * p0, A01 = p3 * p1, A02 = p3 * p2;
    float A10 = p3 * p1, A11 = p3 * p0, A12 = p3 * p1;
    float A20 = p3 * p2, A21 = p3 * p1, A22 = p3 * p0;

    float sm0 = fast_sigmoid(pars[4]);
    float sm1 = fast_sigmoid(pars[5]);
    float sf0 = fast_sigmoid(pars[6]);
    float sf1 = fast_sigmoid(pars[7]);
    float V   = fast_exp(pars[8]);

    float rc0 = m0 * sm0, rc1 = m1 * sm1, rc2 = m2;   // row targets
    float cc0 = m3 * sf0, cc1 = m4 * sf1, cc2 = m5;   // col targets
    float mum0_0 = m0 * (1.0f - sm0);
    float mum0_1 = m1 * (1.0f - sm1);
    float mu0f_0 = m3 * (1.0f - sf0);
    float mu0f_1 = m4 * (1.0f - sf1);

    // ---- Sinkhorn: 10 iterations (register-resident 3x3, scalar) ----
#pragma unroll
    for (int it = 0; it < 10; ++it) {
        float f0 = rc0 * fast_rcp(A00 + A01 + A02 + SEPS);
        float f1 = rc1 * fast_rcp(A10 + A11 + A12 + SEPS);
        float f2 = rc2 * fast_rcp(A20 + A21 + A22 + SEPS);
        A00 *= f0; A01 *= f0; A02 *= f0;
        A10 *= f1; A11 *= f1; A12 *= f1;
        A20 *= f2; A21 *= f2; A22 *= f2;
        float g0 = cc0 * fast_rcp(A00 + A10 + A20 + SEPS);
        float g1 = cc1 * fast_rcp(A01 + A11 + A21 + SEPS);
        float g2 = cc2 * fast_rcp(A02 + A12 + A22 + SEPS);
        A00 *= g0; A10 *= g0; A20 *= g0;
        A01 *= g1; A11 *= g1; A21 *= g1;
        A02 *= g2; A12 *= g2; A22 *= g2;
    }

    // ---- output: mus (4x4 row-major) then V ----
    float4* o = reinterpret_cast<float4*>(out_mus + (size_t)r * 16);
    o[0] = make_float4(A00, A01, A02, mum0_0);
    o[1] = make_float4(A10, A11, A12, mum0_1);
    o[2] = make_float4(A20, A21, A22, 0.0f);
    o[3] = make_float4(mu0f_0, mu0f_1, 0.0f, 0.0f);
    out_V[r] = V;
}

extern "C" void kernel_launch(void* const* d_in, const int* in_sizes, int n_in,
                              void* d_out, int out_size, void* d_ws, size_t ws_size,
                              hipStream_t stream) {
    const float* margins = (const float*)d_in[0];
    const float* W1 = (const float*)d_in[1];
    const float* b1 = (const float*)d_in[2];
    const float* W2 = (const float*)d_in[3];
    const float* b2 = (const float*)d_in[4];
    const float* W3 = (const float*)d_in[5];
    const float* b3 = (const float*)d_in[6];
    const float* W4 = (const float*)d_in[7];
    const float* b4 = (const float*)d_in[8];

    int n = in_sizes[0] / 6;
    float* out_mus = (float*)d_out;
    float* out_V   = out_mus + (size_t)n * 16;
    float* ws      = (float*)d_ws;   // needs 704 floats = 2816 B

    sinkhorn_prep_kernel<<<1, 256, 0, stream>>>(W1, b1, W4, ws);

    dim3 block(256);
    dim3 grid((n + 255) / 256);
    sinkhorn_mlp_kernel<<<grid, block, 0, stream>>>(
        margins, ws, W2, b2, W3, b3, ws + 512, b4, out_mus, out_V, n);
}